// Round 17
// baseline (112.731 us; speedup 1.0000x reference)
//
#include <hip/hip_runtime.h>
#include <hip/hip_bf16.h>

#define B_DIM 256
#define I_DIM 128
#define O_DIM 128
#define H_DIM 32
#define F_DIM 7
#define IBLK 16                   // i's per block
#define SUB 4                     // i's per subchunk
#define NSUB (IBLK / SUB)         // 4
#define NCH_WS (I_DIM / IBLK)     // 8 ws chunks

typedef __attribute__((ext_vector_type(8))) short short8;   // 8 bf16 (4 VGPRs)
typedef __attribute__((ext_vector_type(4))) float float4v;  // MFMA C/D

__device__ inline short bf16s(float v) {
    union { __hip_bfloat16 h; short s; } u;
    u.h = __float2bfloat16(v);
    return u.s;
}

// VALU cross-lane add via DPP (no DS pipe).
template <int CTRL>
__device__ __forceinline__ float dppadd(float v) {
    int s = __builtin_amdgcn_update_dpp(0, __builtin_bit_cast(int, v),
                                        CTRL, 0xF, 0xF, true);
    return v + __builtin_bit_cast(float, s);
}
__device__ __forceinline__ float rowsum16(float v) {
    v = dppadd<0xB1>(v);    // quad_perm [1,0,3,2]
    v = dppadd<0x4E>(v);    // quad_perm [2,3,0,1]
    v = dppadd<0x141>(v);   // row_half_mirror
    v = dppadd<0x140>(v);   // row_mirror
    return v;
}

// R17: single-generation, software-pipelined block.
// R13-R16 post-mortem: busy ~29us (near the ~25us silu/trig issue floor),
// idle ~13us invariant to occupancy (R13=R14), DS-epilogue removal (R16),
// async DMA (R15). Remaining structural source: the >=2 sequential block
// GENERATIONS — at each gen boundary every wave drains on barrier-exposed
// W1 HBM staging (~900cyc) with no resident compute to cover it.
// R17: grid 1024 = exactly 4 blocks/CU, ALL resident (one generation).
// Each block: 16 i's = 4 subchunks, ping-pong LDS; subchunk s+1's W1/B1/W2
// register-prefetched (13 regs) BEFORE compute(s) -> HBM latency drains
// behind ~2800cyc of compute. Compute body identical to R16 (VGPR 36).
//
// REGISTER-PRESSURE LAW (R2/R4/R5): __launch_bounds__(256,w) hard-caps VGPR
// at 256/w; allocator SPILLS to meet it. Body 36 + prefetch ~13 + addr ~5
// = ~54 under (256,4)'s cap 64. Loops rolled (unroll 1) per R4.
template <bool USE_WS>
__global__ __launch_bounds__(256, 4)
void fcnkan_mfma(const float* __restrict__ x,
                 const float* __restrict__ W1,
                 const float* __restrict__ W2,
                 const float* __restrict__ B1,
                 const float* __restrict__ B2,
                 float* __restrict__ ws,
                 float* __restrict__ out) {
    __shared__ __align__(16) short feat_s[2][SUB * B_DIM * 8];       // 2x16 KB
    __shared__ __align__(16) short w1_s[2][(SUB * H_DIM + 1) * 8];   // +1 zero row
    __shared__ float b1_s[2][SUB * H_DIM];
    __shared__ float w2_s[2][SUB * H_DIM];

    const int tid  = threadIdx.x;
    const int o    = blockIdx.x;
    const int i0   = blockIdx.y * IBLK;
    const int w    = tid >> 6;       // wave
    const int lane = tid & 63;
    const int m    = lane & 15;
    const int q    = lane >> 4;

    const short8 zero8 = {};
    const int ZROW = SUB * H_DIM;    // 128

    if (tid == 254) {                // zero rows, both buffers, before barrier
        *reinterpret_cast<short8*>(&w1_s[0][ZROW * 8]) = zero8;
        *reinterpret_cast<short8*>(&w1_s[1][ZROW * 8]) = zero8;
    }

    const int pil = tid >> 5, ph = tid & 31;   // W1-staging role (tid<128)
    const float4* xrow = reinterpret_cast<const float4*>(x + (size_t)tid * I_DIM + i0);

    // ---- prefetch + stage subchunk 0 ----
    float4 px = xrow[0];
    float wr[F_DIM], b1r = 0.f, w2r = 0.f;
    if (tid < 128) {
        size_t iob = ((size_t)(i0 + pil) * O_DIM + o);
        const float* wp = W1 + iob * (H_DIM * F_DIM) + ph * F_DIM;
        #pragma unroll
        for (int f = 0; f < F_DIM; ++f) wr[f] = wp[f];
        b1r = B1[iob * H_DIM + ph];
        w2r = W2[iob * H_DIM + ph];
    }
    {
        float xr[4] = {px.x, px.y, px.z, px.w};
        #pragma unroll
        for (int il = 0; il < SUB; ++il) {
            float xv = xr[il];
            float s1 = __sinf(xv), c1 = __cosf(xv);
            float s2 = 2.f * s1 * c1, c2 = 1.f - 2.f * s1 * s1;
            float s4 = 2.f * s2 * c2, c4 = 1.f - 2.f * s2 * s2;
            short8 a;
            a[0] = bf16s(xv); a[1] = bf16s(s1); a[2] = bf16s(s2); a[3] = bf16s(s4);
            a[4] = bf16s(c1); a[5] = bf16s(c2); a[6] = bf16s(c4); a[7] = 0;
            *reinterpret_cast<short8*>(&feat_s[0][(il * B_DIM + tid) * 8]) = a;
        }
        if (tid < 128) {
            short8 bfr;
            #pragma unroll
            for (int f = 0; f < F_DIM; ++f) bfr[f] = bf16s(wr[f]);
            bfr[7] = 0;
            *reinterpret_cast<short8*>(&w1_s[0][tid * 8]) = bfr;
            b1_s[0][tid] = b1r;
            w2_s[0][tid] = w2r;
        }
    }
    __syncthreads();

    float acc[16];
    #pragma unroll
    for (int r = 0; r < 16; ++r) acc[r] = 0.f;

    #pragma unroll 1
    for (int s = 0; s < NSUB; ++s) {
        const int p = s & 1;

        // ---- issue prefetch for subchunk s+1 (drains behind compute) ----
        if (s + 1 < NSUB) {
            px = xrow[s + 1];
            if (tid < 128) {
                size_t iob = ((size_t)(i0 + (s + 1) * SUB + pil) * O_DIM + o);
                const float* wp = W1 + iob * (H_DIM * F_DIM) + ph * F_DIM;
                #pragma unroll
                for (int f = 0; f < F_DIM; ++f) wr[f] = wp[f];
                b1r = B1[iob * H_DIM + ph];
                w2r = W2[iob * H_DIM + ph];
            }
        }

        // ---- compute subchunk s (R16 body) ----
        #pragma unroll 1
        for (int il = 0; il < SUB; ++il) {
            const short8* fS   = reinterpret_cast<const short8*>(&feat_s[p][0]) + il * B_DIM;
            const short8* wAll = reinterpret_cast<const short8*>(&w1_s[p][0]);

            short8 afrag[4];
            #pragma unroll
            for (int t = 0; t < 4; ++t)
                afrag[t] = fS[w * 64 + t * 16 + m];

            short8 bfrag[2];
            float  b1v[2], w2v[2];
            #pragma unroll
            for (int nt = 0; nt < 2; ++nt) {
                int h = nt * 16 + m;
                int idx = (q == 0) ? (il * H_DIM + h) : ZROW;
                bfrag[nt] = wAll[idx];
                b1v[nt] = b1_s[p][il * H_DIM + h];
                w2v[nt] = w2_s[p][il * H_DIM + h];
            }

            #pragma unroll
            for (int nt = 0; nt < 2; ++nt) {
                float4v c0 = {b1v[nt], b1v[nt], b1v[nt], b1v[nt]};
                #pragma unroll
                for (int t = 0; t < 4; ++t) {
                    float4v z = __builtin_amdgcn_mfma_f32_16x16x32_bf16(
                        afrag[t], bfrag[nt], c0, 0, 0, 0);
                    #pragma unroll
                    for (int r = 0; r < 4; ++r) {
                        float zz = z[r];
                        float sg = __builtin_amdgcn_rcpf(1.f + __expf(-zz));
                        acc[t * 4 + r] = fmaf(zz * sg, w2v[nt], acc[t * 4 + r]);
                    }
                }
            }
        }

        // ---- stage subchunk s+1 into the other buffer ----
        if (s + 1 < NSUB) {
            const int pn = (s + 1) & 1;
            float xr[4] = {px.x, px.y, px.z, px.w};
            #pragma unroll
            for (int il = 0; il < SUB; ++il) {
                float xv = xr[il];
                float s1 = __sinf(xv), c1 = __cosf(xv);
                float s2 = 2.f * s1 * c1, c2 = 1.f - 2.f * s1 * s1;
                float s4 = 2.f * s2 * c2, c4 = 1.f - 2.f * s2 * s2;
                short8 a;
                a[0] = bf16s(xv); a[1] = bf16s(s1); a[2] = bf16s(s2); a[3] = bf16s(s4);
                a[4] = bf16s(c1); a[5] = bf16s(c2); a[6] = bf16s(c4); a[7] = 0;
                *reinterpret_cast<short8*>(&feat_s[pn][(il * B_DIM + tid) * 8]) = a;
            }
            if (tid < 128) {
                short8 bfr;
                #pragma unroll
                for (int f = 0; f < F_DIM; ++f) bfr[f] = bf16s(wr[f]);
                bfr[7] = 0;
                *reinterpret_cast<short8*>(&w1_s[pn][tid * 8]) = bfr;
                b1_s[pn][tid] = b1r;
                w2_s[pn][tid] = w2r;
            }
        }
        __syncthreads();
    }

    // ---- h-sum via DPP (VALU only) ----
    #pragma unroll
    for (int r = 0; r < 16; ++r) acc[r] = rowsum16(acc[r]);

    // B2 contribution over all 16 i's
    float b2c = 0.f;
    #pragma unroll 1
    for (int il = 0; il < IBLK; ++il) b2c += B2[(size_t)(i0 + il) * O_DIM + o];

    if (m == 0) {
        if (USE_WS) {
            float* wsp = ws + ((size_t)blockIdx.y * O_DIM + o) * B_DIM;
            #pragma unroll
            for (int t = 0; t < 4; ++t)
                #pragma unroll
                for (int r = 0; r < 4; ++r)
                    wsp[w * 64 + t * 16 + q * 4 + r] = acc[t * 4 + r] + b2c;
        } else {
            #pragma unroll
            for (int t = 0; t < 4; ++t)
                #pragma unroll
                for (int r = 0; r < 4; ++r) {
                    int b = w * 64 + t * 16 + q * 4 + r;
                    atomicAdd(&out[(size_t)b * O_DIM + o], acc[t * 4 + r] + b2c);
                }
        }
    }
}

// Sum the NCH_WS partials per (o,b). Coalesced; 1 MB, L2-resident.
__global__ __launch_bounds__(256)
void reduce_kernel(const float* __restrict__ ws, float* __restrict__ out) {
    const int o = blockIdx.x;
    const int b = threadIdx.x;
    float s = 0.f;
    #pragma unroll
    for (int c = 0; c < NCH_WS; ++c)
        s += ws[((size_t)c * O_DIM + o) * B_DIM + b];
    out[(size_t)b * O_DIM + o] = s;
}

extern "C" void kernel_launch(void* const* d_in, const int* in_sizes, int n_in,
                              void* d_out, int out_size, void* d_ws, size_t ws_size,
                              hipStream_t stream) {
    const float* x  = (const float*)d_in[0];
    const float* W1 = (const float*)d_in[1];
    const float* W2 = (const float*)d_in[2];
    const float* B1 = (const float*)d_in[3];
    const float* B2 = (const float*)d_in[4];
    float* out = (float*)d_out;
    float* ws  = (float*)d_ws;

    const size_t ws_need = (size_t)NCH_WS * O_DIM * B_DIM * sizeof(float); // 1 MiB
    dim3 grid(O_DIM, I_DIM / IBLK);   // (128, 8) = 1024 blocks, all resident
    if (ws_size >= ws_need) {   // launch-invariant -> graph-safe
        fcnkan_mfma<true><<<grid, 256, 0, stream>>>(x, W1, W2, B1, B2, ws, out);
        reduce_kernel<<<O_DIM, B_DIM, 0, stream>>>(ws, out);
    } else {
        hipMemsetAsync(out, 0, (size_t)out_size * sizeof(float), stream);
        fcnkan_mfma<false><<<grid, 256, 0, stream>>>(x, W1, W2, B1, B2, ws, out);
    }
}